// Round 5
// baseline (634.803 us; speedup 1.0000x reference)
//
#include <hip/hip_runtime.h>
#include <hip/hip_bf16.h>
#include <math.h>
#include <stdint.h>

#define NN 50000
#define NE 500000
#define DIN 264
#define KP1 288      // DIN padded to multiple of 32
#define HID 128
#define EDIM 16

typedef __attribute__((ext_vector_type(8))) short short8;
typedef __attribute__((ext_vector_type(4))) float f32x4;

__device__ __forceinline__ short f2bf(float v) {
    union { float f; unsigned u; } x; x.f = v;
    unsigned r = x.u + 0x7fff + ((x.u >> 16) & 1);
    return (short)(r >> 16);
}
__device__ __forceinline__ float bf2f(short v) {
    union { float f; unsigned u; } x;
    x.u = ((unsigned)(unsigned short)v) << 16;
    return x.f;
}
__device__ __forceinline__ float lo_bf(unsigned u) {
    union { float f; unsigned u; } x; x.u = u << 16; return x.f;
}
__device__ __forceinline__ float hi_bf(unsigned u) {
    union { float f; unsigned u; } x; x.u = u & 0xffff0000u; return x.f;
}

__device__ __forceinline__ void gload_lds16(const void* g, void* l) {
    __builtin_amdgcn_global_load_lds(
        (const __attribute__((address_space(1))) unsigned int*)g,
        (__attribute__((address_space(3))) unsigned int*)l, 16, 0, 0);
}

// ---------------- CSR build (dst -> in-edges) ----------------
__global__ void k_count(const int* __restrict__ dst, int* __restrict__ cnt) {
    int e = blockIdx.x * blockDim.x + threadIdx.x;
    if (e < NE) atomicAdd(&cnt[dst[e]], 1);
}

__global__ __launch_bounds__(256) void k_scan1(const int* __restrict__ cnt,
                                               int* __restrict__ off, int* __restrict__ bsum) {
    __shared__ int buf[256];
    int b = blockIdx.x, t = threadIdx.x;
    int i = b * 256 + t;
    int v = (i < NN) ? cnt[i] : 0;
    buf[t] = v; __syncthreads();
    for (int s = 1; s < 256; s <<= 1) {
        int u = (t >= s) ? buf[t - s] : 0; __syncthreads();
        buf[t] += u; __syncthreads();
    }
    if (i < NN) off[i + 1] = buf[t];
    if (t == 255) bsum[b] = buf[255];
}

__global__ void k_scan2(int* __restrict__ bsum, int nb) {
    __shared__ int buf[256];
    int t = threadIdx.x;
    int o = (t < nb) ? bsum[t] : 0;
    buf[t] = o; __syncthreads();
    for (int s = 1; s < 256; s <<= 1) {
        int u = (t >= s) ? buf[t - s] : 0; __syncthreads();
        buf[t] += u; __syncthreads();
    }
    if (t < nb) bsum[t] = buf[t] - o;   // exclusive
}

__global__ void k_scan3(int* __restrict__ off, const int* __restrict__ bsum) {
    int i = blockIdx.x * 256 + threadIdx.x;
    if (i < NN) off[i + 1] += bsum[i >> 8];
    if (i == 0) off[0] = 0;
}

__global__ void k_copyoff(const int* __restrict__ off, int* __restrict__ cur) {
    int i = blockIdx.x * blockDim.x + threadIdx.x;
    if (i < NN) cur[i] = off[i];
}

__global__ void k_scatter(const int* __restrict__ src, const int* __restrict__ dst,
                          int* __restrict__ cur, int2* __restrict__ csr_se) {
    int e = blockIdx.x * blockDim.x + threadIdx.x;
    if (e < NE) {
        int d = dst[e];
        int p = atomicAdd(&cur[d], 1);
        csr_se[p] = make_int2(src[e], e);
    }
}

// ---------------- weight/bias/input prep ----------------
__global__ void k_cvt_x(const float* __restrict__ x, short* __restrict__ xb) {
    int idx = blockIdx.x * 256 + threadIdx.x;
    if (idx >= NN * KP1) return;
    int i = idx / KP1, k = idx - i * KP1;
    xb[idx] = (k < DIN) ? f2bf(x[(size_t)i * DIN + k]) : (short)0;
}

__global__ void k_build_bt1(const float* __restrict__ Wl, const float* __restrict__ Wr,
                            const float* __restrict__ Wres, short* __restrict__ Bt) {
    int idx = blockIdx.x * 256 + threadIdx.x;   // 384*288
    if (idx >= 384 * KP1) return;
    int n = idx / KP1, k = idx - n * KP1;
    float v = 0.f;
    if (k < DIN) {
        const float* W = (n < 128) ? Wl : ((n < 256) ? Wr : Wres);
        v = W[(size_t)k * 128 + (n & 127)];
    }
    Bt[idx] = f2bf(v);
}

__global__ void k_build_bt2(const float* __restrict__ Wl, const float* __restrict__ Wr,
                            short* __restrict__ Bt) {
    int idx = blockIdx.x * 256 + threadIdx.x;   // 256*128
    if (idx >= 256 * 128) return;
    int n = idx >> 7, k = idx & 127;
    const float* W = (n < 128) ? Wl : Wr;
    Bt[idx] = f2bf(W[(size_t)k * 128 + (n & 127)]);
}

__global__ void k_build_bt3(const float* __restrict__ W, short* __restrict__ Bt) {
    int idx = blockIdx.x * 256 + threadIdx.x;   // 128*128
    if (idx >= 128 * 128) return;
    int n = idx >> 7, k = idx & 127;
    Bt[idx] = f2bf(W[(size_t)k * 128 + n]);
}

__global__ void k_cat3(const float* a, const float* b, const float* c, float* o) {
    int t = threadIdx.x;   // 384
    o[t] = (t < 128) ? a[t] : ((t < 256) ? b[t - 128] : c[t - 256]);
}

__global__ void k_cat2(const float* a, const float* b, float* o) {
    int t = threadIdx.x;   // 256
    o[t] = (t < 128) ? a[t] : b[t - 128];
}

// ---------------- bf16 MFMA GEMM: C[M x NS] = A[M x Kpad] @ Bt[NS x Kpad]^T + bias ----------------
template <bool BF16OUT>
__global__ __launch_bounds__(256) void k_mfma_gemm(const short* __restrict__ A,
                                                   const short* __restrict__ Bt,
                                                   const float* __restrict__ bias,
                                                   float* __restrict__ Cf,
                                                   short* __restrict__ Cb,
                                                   int M, int Kpad, int NS) {
    __shared__ short As[128 * 32];
    __shared__ short Bs[128 * 32];
    int t = threadIdx.x;
    int lane = t & 63, wid = t >> 6;
    int wm = (wid & 1) * 64, wn = (wid >> 1) * 64;
    int cl = lane & 15, quad = lane >> 4;
    int row0 = blockIdx.x * 128;
    int col0 = blockIdx.y * 128;

    f32x4 acc[4][4];
#pragma unroll
    for (int i = 0; i < 4; ++i)
#pragma unroll
        for (int j = 0; j < 4; ++j) acc[i][j] = (f32x4)0.f;

    for (int k0 = 0; k0 < Kpad; k0 += 32) {
#pragma unroll
        for (int r = 0; r < 2; ++r) {
            int c = t + r * 256;                     // chunk 0..511
            int m = c >> 2;
            int row = row0 + m; if (row >= M) row = M - 1;
            const char* ga = (const char*)A + ((size_t)row * Kpad + k0) * 2 + (c & 3) * 16;
            gload_lds16(ga, (char*)As + c * 16);
            int n = col0 + m;
            const char* gb = (const char*)Bt + ((size_t)n * Kpad + k0) * 2 + (c & 3) * 16;
            gload_lds16(gb, (char*)Bs + c * 16);
        }
        __syncthreads();

        short8 a[4], b[4];
#pragma unroll
        for (int mi = 0; mi < 4; ++mi)
            a[mi] = *(const short8*)&As[(wm + mi * 16 + cl) * 32 + quad * 8];
#pragma unroll
        for (int ni = 0; ni < 4; ++ni)
            b[ni] = *(const short8*)&Bs[(wn + ni * 16 + cl) * 32 + quad * 8];
#pragma unroll
        for (int mi = 0; mi < 4; ++mi)
#pragma unroll
            for (int ni = 0; ni < 4; ++ni)
                acc[mi][ni] = __builtin_amdgcn_mfma_f32_16x16x32_bf16(a[mi], b[ni], acc[mi][ni], 0, 0, 0);
        __syncthreads();
    }

#pragma unroll
    for (int mi = 0; mi < 4; ++mi)
#pragma unroll
        for (int ni = 0; ni < 4; ++ni) {
            int col = col0 + wn + ni * 16 + cl;
            float bv = bias[col];
#pragma unroll
            for (int r = 0; r < 4; ++r) {
                int row = row0 + wm + mi * 16 + quad * 4 + r;
                if (row < M) {
                    float v = acc[mi][ni][r] + bv;
                    if (BF16OUT) Cb[(size_t)row * NS + col] = f2bf(v);
                    else         Cf[(size_t)row * NS + col] = v;
                }
            }
        }
}

// ---------------- block helpers ----------------
__device__ __forceinline__ float block_sum128(float v, volatile float* red) {
#pragma unroll
    for (int o = 32; o > 0; o >>= 1) v += __shfl_down(v, o, 64);
    int w = threadIdx.x >> 6;
    __syncthreads();
    if ((threadIdx.x & 63) == 0) red[w] = v;
    __syncthreads();
    return red[0] + red[1];
}

// ---------------- fused edge-score + softmax aggregate + epilogue ----------------
// One block (128 thr = 4 groups of 32 lanes) per dst node i.
// Group g handles edges b0+g, b0+g+4, ... Thread q in group owns features 4q..4q+3.
// Softmax without max-subtraction (scores are O(1)): l += exp(s); acc += exp(s)*xl.
// Group partials merged via LDS; epilogue: +bias, ELU, +residual, LayerNorm, bf16 store.
template <int STRIDE>
__global__ __launch_bounds__(128) void k_fused_agg(const int* __restrict__ off,
                                                   const int2* __restrict__ csr_se,
                                                   const short* __restrict__ C,
                                                   const float* __restrict__ ea,
                                                   const float* __restrict__ We,
                                                   const float* __restrict__ att,
                                                   const short* __restrict__ resid, int rstride,
                                                   const float* __restrict__ bias,
                                                   const float* __restrict__ gamma,
                                                   const float* __restrict__ beta,
                                                   short* __restrict__ outb) {
    __shared__ float accS[4][128];
    __shared__ float lS[4][4];
    __shared__ float red[2];

    int i = blockIdx.x;
    int t = threadIdx.x;
    int lane = t & 63;
    int g = (t >> 6) * 2 + (lane >> 5);   // group 0..3
    int q = lane & 31;                    // lane in group
    int fb = q * 4;                       // feature base (4 consecutive)
    int b0 = off[i], b1 = off[i + 1];

    // We columns for my 4 features: 16 x float4
    float4 w4[16];
#pragma unroll
    for (int k = 0; k < EDIM; ++k) w4[k] = *(const float4*)(We + k * 128 + fb);
    float4 attv = *(const float4*)(att + fb);

    // xr for this node's 4 features
    uint2 xru = *(const uint2*)(C + (size_t)i * STRIDE + 128 + fb);
    float xr0 = lo_bf(xru.x), xr1 = hi_bf(xru.x), xr2 = lo_bf(xru.y), xr3 = hi_bf(xru.y);

    float l_run = 0.f;
    float a0 = 0.f, a1 = 0.f, a2 = 0.f, a3 = 0.f;

    for (int pos = b0 + g; pos < b1; pos += 4) {
        int2 se = csr_se[pos];
        int s = se.x, e = se.y;
        const float4* ea4 = (const float4*)(ea + (size_t)e * EDIM);
        float4 A0 = ea4[0], A1 = ea4[1], A2 = ea4[2], A3 = ea4[3];
        float ev[16] = {A0.x, A0.y, A0.z, A0.w, A1.x, A1.y, A1.z, A1.w,
                        A2.x, A2.y, A2.z, A2.w, A3.x, A3.y, A3.z, A3.w};
        uint2 xu = *(const uint2*)(C + (size_t)s * STRIDE + fb);
        float x0 = lo_bf(xu.x), x1 = hi_bf(xu.x), x2 = lo_bf(xu.y), x3 = hi_bf(xu.y);
        float m0 = x0 + xr0, m1 = x1 + xr1, m2 = x2 + xr2, m3 = x3 + xr3;
#pragma unroll
        for (int k = 0; k < EDIM; ++k) {
            m0 = fmaf(ev[k], w4[k].x, m0);
            m1 = fmaf(ev[k], w4[k].y, m1);
            m2 = fmaf(ev[k], w4[k].z, m2);
            m3 = fmaf(ev[k], w4[k].w, m3);
        }
        // leaky relu + dot with att
        float g0 = fmaxf(m0, 0.f) + 0.2f * fminf(m0, 0.f);
        float g1 = fmaxf(m1, 0.f) + 0.2f * fminf(m1, 0.f);
        float g2 = fmaxf(m2, 0.f) + 0.2f * fminf(m2, 0.f);
        float g3 = fmaxf(m3, 0.f) + 0.2f * fminf(m3, 0.f);
        float p = g0 * attv.x + g1 * attv.y + g2 * attv.z + g3 * attv.w;
        // head sum over 8 lanes (features of one head span 8 lanes)
        p += __shfl_xor(p, 1, 64);
        p += __shfl_xor(p, 2, 64);
        p += __shfl_xor(p, 4, 64);
        float pe = __expf(p);
        l_run += pe;
        a0 = fmaf(pe, x0, a0);
        a1 = fmaf(pe, x1, a1);
        a2 = fmaf(pe, x2, a2);
        a3 = fmaf(pe, x3, a3);
    }

    // merge 4 groups
    *(float4*)&accS[g][fb] = make_float4(a0, a1, a2, a3);
    if ((q & 7) == 0) lS[g][q >> 3] = l_run;
    __syncthreads();

    int hh = t >> 5;
    float asum = accS[0][t] + accS[1][t] + accS[2][t] + accS[3][t];
    float lsum = lS[0][hh] + lS[1][hh] + lS[2][hh] + lS[3][hh];

    float o = asum / (lsum + 1e-16f) + bias[t];
    o = o > 0.f ? o : (__expf(o) - 1.f);                 // ELU
    float v = o + bf2f(resid[(size_t)i * rstride + t]);  // + residual
    float mean = block_sum128(v, red) * (1.f / 128.f);
    float d = v - mean;
    float var = block_sum128(d * d, red) * (1.f / 128.f);
    float r = d * rsqrtf(var + 1e-5f) * gamma[t] + beta[t];
    outb[(size_t)i * 128 + t] = f2bf(r);
}

// ---------------- plain LN over 128 ----------------
__global__ __launch_bounds__(128) void k_ln(const float* __restrict__ in,
                                            const float* __restrict__ gamma,
                                            const float* __restrict__ beta,
                                            float* __restrict__ out) {
    __shared__ float red[2];
    int i = blockIdx.x, t = threadIdx.x;
    float v = in[(size_t)i * 128 + t];
    float mean = block_sum128(v, red) * (1.f / 128.f);
    float d = v - mean;
    float var = block_sum128(d * d, red) * (1.f / 128.f);
    out[(size_t)i * 128 + t] = d * rsqrtf(var + 1e-5f) * gamma[t] + beta[t];
}

extern "C" void kernel_launch(void* const* d_in, const int* in_sizes, int n_in,
                              void* d_out, int out_size, void* d_ws, size_t ws_size,
                              hipStream_t stream) {
    (void)in_sizes; (void)n_in; (void)out_size; (void)ws_size;
    const float* x     = (const float*)d_in[0];
    const float* ea    = (const float*)d_in[1];
    const float* Wl1   = (const float*)d_in[2];
    const float* bl1   = (const float*)d_in[3];
    const float* Wr1   = (const float*)d_in[4];
    const float* br1   = (const float*)d_in[5];
    const float* We1   = (const float*)d_in[6];
    const float* att1  = (const float*)d_in[7];
    const float* bias1 = (const float*)d_in[8];
    const float* Wl2   = (const float*)d_in[9];
    const float* bl2   = (const float*)d_in[10];
    const float* Wr2   = (const float*)d_in[11];
    const float* br2   = (const float*)d_in[12];
    const float* We2   = (const float*)d_in[13];
    const float* att2  = (const float*)d_in[14];
    const float* bias2 = (const float*)d_in[15];
    const float* Wres  = (const float*)d_in[16];
    const float* bres  = (const float*)d_in[17];
    const float* Wout  = (const float*)d_in[18];
    const float* bout  = (const float*)d_in[19];
    const float* g1    = (const float*)d_in[20];
    const float* bn1   = (const float*)d_in[21];
    const float* g2    = (const float*)d_in[22];
    const float* bn2   = (const float*)d_in[23];
    const float* go    = (const float*)d_in[24];
    const float* bo    = (const float*)d_in[25];
    const int*   ei    = (const int*)d_in[26];
    const int* srcv = ei;
    const int* dstv = ei + NE;
    float* outp = (float*)d_out;

    char* p = (char*)d_ws;
    auto carve = [&](size_t bytes) {
        char* r = p;
        p += (bytes + 255) & ~(size_t)255;
        return r;
    };
    short* xb    = (short*)carve((size_t)NN * KP1 * 2);
    short* Wt1   = (short*)carve((size_t)384 * KP1 * 2);
    short* Wt2   = (short*)carve((size_t)256 * 128 * 2);
    short* Wt3   = (short*)carve((size_t)128 * 128 * 2);
    float* bcat1 = (float*)carve(384 * 4);
    float* bcat2 = (float*)carve(256 * 4);
    short* C1    = (short*)carve((size_t)NN * 384 * 2);   // bf16 [xl|xr|res]
    short* h1b   = (short*)carve((size_t)NN * 128 * 2);
    short* h2b   = (short*)carve((size_t)NN * 128 * 2);
    float* C3    = (float*)carve((size_t)NN * 128 * 4);
    int* off     = (int*)carve((size_t)(NN + 1) * 4);
    int* cur     = (int*)carve((size_t)NN * 4);
    int* bsum    = (int*)carve(256 * 4);
    int2* csr_se = (int2*)carve((size_t)NE * 8);

    short* C2 = C1;                                  // stride 256, reuse after layer 1

    const int NB = (NN + 255) / 256;                 // 196

    // ---- CSR build ----
    hipMemsetAsync(cur, 0, (size_t)NN * 4, stream);
    k_count<<<(NE + 255) / 256, 256, 0, stream>>>(dstv, cur);
    k_scan1<<<NB, 256, 0, stream>>>(cur, off, bsum);
    k_scan2<<<1, 256, 0, stream>>>(bsum, NB);
    k_scan3<<<NB, 256, 0, stream>>>(off, bsum);
    k_copyoff<<<NB, 256, 0, stream>>>(off, cur);
    k_scatter<<<(NE + 255) / 256, 256, 0, stream>>>(srcv, dstv, cur, csr_se);

    // ---- prep ----
    k_cvt_x<<<((size_t)NN * KP1 + 255) / 256, 256, 0, stream>>>(x, xb);
    k_build_bt1<<<(384 * KP1 + 255) / 256, 256, 0, stream>>>(Wl1, Wr1, Wres, Wt1);
    k_build_bt2<<<(256 * 128 + 255) / 256, 256, 0, stream>>>(Wl2, Wr2, Wt2);
    k_build_bt3<<<(128 * 128 + 255) / 256, 256, 0, stream>>>(Wout, Wt3);
    k_cat3<<<1, 384, 0, stream>>>(bl1, br1, bres, bcat1);
    k_cat2<<<1, 256, 0, stream>>>(bl2, br2, bcat2);

    int mb = (NN + 127) / 128;                       // 391

    // ---- layer 1 ----
    k_mfma_gemm<true><<<dim3(mb, 3), 256, 0, stream>>>(xb, Wt1, bcat1, nullptr, C1, NN, KP1, 384);
    k_fused_agg<384><<<NN, 128, 0, stream>>>(off, csr_se, C1, ea, We1, att1,
                                             C1 + 256, 384, bias1, g1, bn1, h1b);
    // ---- layer 2 ----
    k_mfma_gemm<true><<<dim3(mb, 2), 256, 0, stream>>>(h1b, Wt2, bcat2, nullptr, C2, NN, 128, 256);
    k_fused_agg<256><<<NN, 128, 0, stream>>>(off, csr_se, C2, ea, We2, att2,
                                             h1b, 128, bias2, g2, bn2, h2b);
    // ---- output ----
    k_mfma_gemm<false><<<dim3(mb, 1), 256, 0, stream>>>(h2b, Wt3, bout, C3, nullptr, NN, 128, 128);
    k_ln<<<NN, 128, 0, stream>>>(C3, go, bo, outp);
}

// Round 6
// 588.582 us; speedup vs baseline: 1.0785x; 1.0785x over previous
//
#include <hip/hip_runtime.h>
#include <hip/hip_bf16.h>
#include <math.h>
#include <stdint.h>

#define NN 50000
#define NE 500000
#define DIN 264
#define KP1 288      // DIN padded to multiple of 32
#define HID 128
#define EDIM 16

typedef __attribute__((ext_vector_type(8))) short short8;
typedef __attribute__((ext_vector_type(4))) float f32x4;

__device__ __forceinline__ short f2bf(float v) {
    union { float f; unsigned u; } x; x.f = v;
    unsigned r = x.u + 0x7fff + ((x.u >> 16) & 1);
    return (short)(r >> 16);
}
__device__ __forceinline__ float bf2f(short v) {
    union { float f; unsigned u; } x;
    x.u = ((unsigned)(unsigned short)v) << 16;
    return x.f;
}

__device__ __forceinline__ void gload_lds16(const void* g, void* l) {
    __builtin_amdgcn_global_load_lds(
        (const __attribute__((address_space(1))) unsigned int*)g,
        (__attribute__((address_space(3))) unsigned int*)l, 16, 0, 0);
}

// ---------------- CSR build (dst -> in-edges) ----------------
__global__ void k_count(const int* __restrict__ dst, int* __restrict__ cnt) {
    int e = blockIdx.x * blockDim.x + threadIdx.x;
    if (e < NE) atomicAdd(&cnt[dst[e]], 1);
}

__global__ __launch_bounds__(256) void k_scan1(const int* __restrict__ cnt,
                                               int* __restrict__ off, int* __restrict__ bsum) {
    __shared__ int buf[256];
    int b = blockIdx.x, t = threadIdx.x;
    int i = b * 256 + t;
    int v = (i < NN) ? cnt[i] : 0;
    buf[t] = v; __syncthreads();
    for (int s = 1; s < 256; s <<= 1) {
        int u = (t >= s) ? buf[t - s] : 0; __syncthreads();
        buf[t] += u; __syncthreads();
    }
    if (i < NN) off[i + 1] = buf[t];
    if (t == 255) bsum[b] = buf[255];
}

__global__ void k_scan2(int* __restrict__ bsum, int nb) {
    __shared__ int buf[256];
    int t = threadIdx.x;
    int o = (t < nb) ? bsum[t] : 0;
    buf[t] = o; __syncthreads();
    for (int s = 1; s < 256; s <<= 1) {
        int u = (t >= s) ? buf[t - s] : 0; __syncthreads();
        buf[t] += u; __syncthreads();
    }
    if (t < nb) bsum[t] = buf[t] - o;   // exclusive
}

// finalize offsets AND copy to cur in one pass
__global__ void k_scan3c(int* __restrict__ off, const int* __restrict__ bsum,
                         int* __restrict__ cur) {
    int j = blockIdx.x * 256 + threadIdx.x;   // 0..NN
    if (j > NN) return;
    int v = (j == 0) ? 0 : off[j] + bsum[(j - 1) >> 8];
    off[j] = v;
    if (j < NN) cur[j] = v;
}

__global__ void k_scatter(const int* __restrict__ src, const int* __restrict__ dst,
                          int* __restrict__ cur, int2* __restrict__ csr_se) {
    int e = blockIdx.x * blockDim.x + threadIdx.x;
    if (e < NE) {
        int d = dst[e];
        int p = atomicAdd(&cur[d], 1);
        csr_se[p] = make_int2(src[e], e);
    }
}

// ---------------- weight/bias/input prep ----------------
__global__ void k_cvt_x(const float* __restrict__ x, short* __restrict__ xb) {
    int idx = blockIdx.x * 256 + threadIdx.x;
    if (idx >= NN * KP1) return;
    int i = idx / KP1, k = idx - i * KP1;
    xb[idx] = (k < DIN) ? f2bf(x[(size_t)i * DIN + k]) : (short)0;
}

// all weight transposes + bias concats in ONE dispatch
__global__ void k_prep_w(const float* __restrict__ Wl1, const float* __restrict__ Wr1,
                         const float* __restrict__ Wres, const float* __restrict__ Wl2,
                         const float* __restrict__ Wr2, const float* __restrict__ Wout,
                         const float* __restrict__ bl1, const float* __restrict__ br1,
                         const float* __restrict__ bres, const float* __restrict__ bl2,
                         const float* __restrict__ br2,
                         short* __restrict__ Wt1, short* __restrict__ Wt2,
                         short* __restrict__ Wt3, float* __restrict__ bcat1,
                         float* __restrict__ bcat2) {
    int idx = blockIdx.x * 256 + threadIdx.x;
    if (idx < 384 * KP1) {
        int n = idx / KP1, k = idx - n * KP1;
        float v = 0.f;
        if (k < DIN) {
            const float* W = (n < 128) ? Wl1 : ((n < 256) ? Wr1 : Wres);
            v = W[(size_t)k * 128 + (n & 127)];
        }
        Wt1[idx] = f2bf(v);
        return;
    }
    idx -= 384 * KP1;
    if (idx < 256 * 128) {
        int n = idx >> 7, k = idx & 127;
        const float* W = (n < 128) ? Wl2 : Wr2;
        Wt2[idx] = f2bf(W[(size_t)k * 128 + (n & 127)]);
        return;
    }
    idx -= 256 * 128;
    if (idx < 128 * 128) {
        int n = idx >> 7, k = idx & 127;
        Wt3[idx] = f2bf(Wout[(size_t)k * 128 + n]);
        return;
    }
    idx -= 128 * 128;
    if (idx < 384) {
        bcat1[idx] = (idx < 128) ? bl1[idx] : ((idx < 256) ? br1[idx - 128] : bres[idx - 256]);
        return;
    }
    idx -= 384;
    if (idx < 256)
        bcat2[idx] = (idx < 128) ? bl2[idx] : br2[idx - 128];
}

// ---------------- bf16 MFMA GEMM: C[M x NS] = A[M x Kpad] @ Bt[NS x Kpad]^T + bias ----------------
template <bool BF16OUT>
__global__ __launch_bounds__(256) void k_mfma_gemm(const short* __restrict__ A,
                                                   const short* __restrict__ Bt,
                                                   const float* __restrict__ bias,
                                                   float* __restrict__ Cf,
                                                   short* __restrict__ Cb,
                                                   int M, int Kpad, int NS) {
    __shared__ short As[128 * 32];
    __shared__ short Bs[128 * 32];
    int t = threadIdx.x;
    int lane = t & 63, wid = t >> 6;
    int wm = (wid & 1) * 64, wn = (wid >> 1) * 64;
    int cl = lane & 15, quad = lane >> 4;
    int row0 = blockIdx.x * 128;
    int col0 = blockIdx.y * 128;

    f32x4 acc[4][4];
#pragma unroll
    for (int i = 0; i < 4; ++i)
#pragma unroll
        for (int j = 0; j < 4; ++j) acc[i][j] = (f32x4)0.f;

    for (int k0 = 0; k0 < Kpad; k0 += 32) {
#pragma unroll
        for (int r = 0; r < 2; ++r) {
            int c = t + r * 256;                     // chunk 0..511
            int m = c >> 2;
            int row = row0 + m; if (row >= M) row = M - 1;
            const char* ga = (const char*)A + ((size_t)row * Kpad + k0) * 2 + (c & 3) * 16;
            gload_lds16(ga, (char*)As + c * 16);
            int n = col0 + m;
            const char* gb = (const char*)Bt + ((size_t)n * Kpad + k0) * 2 + (c & 3) * 16;
            gload_lds16(gb, (char*)Bs + c * 16);
        }
        __syncthreads();

        short8 a[4], b[4];
#pragma unroll
        for (int mi = 0; mi < 4; ++mi)
            a[mi] = *(const short8*)&As[(wm + mi * 16 + cl) * 32 + quad * 8];
#pragma unroll
        for (int ni = 0; ni < 4; ++ni)
            b[ni] = *(const short8*)&Bs[(wn + ni * 16 + cl) * 32 + quad * 8];
#pragma unroll
        for (int mi = 0; mi < 4; ++mi)
#pragma unroll
            for (int ni = 0; ni < 4; ++ni)
                acc[mi][ni] = __builtin_amdgcn_mfma_f32_16x16x32_bf16(a[mi], b[ni], acc[mi][ni], 0, 0, 0);
        __syncthreads();
    }

#pragma unroll
    for (int mi = 0; mi < 4; ++mi)
#pragma unroll
        for (int ni = 0; ni < 4; ++ni) {
            int col = col0 + wn + ni * 16 + cl;
            float bv = bias[col];
#pragma unroll
            for (int r = 0; r < 4; ++r) {
                int row = row0 + wm + mi * 16 + quad * 4 + r;
                if (row < M) {
                    float v = acc[mi][ni][r] + bv;
                    if (BF16OUT) Cb[(size_t)row * NS + col] = f2bf(v);
                    else         Cf[(size_t)row * NS + col] = v;
                }
            }
        }
}

// ---------------- block helpers ----------------
__device__ __forceinline__ float block_sum128(float v, volatile float* red) {
#pragma unroll
    for (int o = 32; o > 0; o >>= 1) v += __shfl_down(v, o, 64);
    int w = threadIdx.x >> 6;
    __syncthreads();
    if ((threadIdx.x & 63) == 0) red[w] = v;
    __syncthreads();
    return red[0] + red[1];
}

// ---------------- fused edge-score + softmax aggregate + epilogue ----------------
// One block (128 thr) per NPB consecutive dst nodes; thread t owns feature t.
// Plain-sum softmax (scores are O(1): no max-subtraction, so edge iterations are
// independent -> compiler can pipeline the gathers). src/eid wave-uniform via
// readfirstlane -> ea rows are s_loads, xl gather is saddr-form (no VALU addr math).
template <int STRIDE, int NPB>
__global__ __launch_bounds__(128) void k_fused_agg(const int* __restrict__ off,
                                                   const int2* __restrict__ csr_se,
                                                   const short* __restrict__ C,
                                                   const float* __restrict__ ea,
                                                   const float* __restrict__ We,
                                                   const float* __restrict__ att,
                                                   const short* __restrict__ resid, int rstride,
                                                   const float* __restrict__ bias,
                                                   const float* __restrict__ gamma,
                                                   const float* __restrict__ beta,
                                                   short* __restrict__ outb) {
    __shared__ float red[2];
    int t = threadIdx.x;

    float wreg[EDIM];
#pragma unroll
    for (int k = 0; k < EDIM; ++k) wreg[k] = We[k * 128 + t];
    float att_t = att[t], bias_t = bias[t], gamma_t = gamma[t], beta_t = beta[t];

    for (int n = 0; n < NPB; ++n) {
        int i = blockIdx.x * NPB + n;
        int b0 = off[i], b1 = off[i + 1];
        float xr_t = bf2f(C[(size_t)i * STRIDE + 128 + t]);

        float l_run = 0.f, acc = 0.f;
        for (int pos = b0; pos < b1; ++pos) {
            int2 se = csr_se[pos];
            int s = __builtin_amdgcn_readfirstlane(se.x);
            int e = __builtin_amdgcn_readfirstlane(se.y);
            const float* ep = ea + (size_t)e * EDIM;
            float e0 = 0.f, e1 = 0.f, e2 = 0.f, e3 = 0.f;
#pragma unroll
            for (int k = 0; k < EDIM; k += 4) {
                e0 = fmaf(ep[k + 0], wreg[k + 0], e0);
                e1 = fmaf(ep[k + 1], wreg[k + 1], e1);
                e2 = fmaf(ep[k + 2], wreg[k + 2], e2);
                e3 = fmaf(ep[k + 3], wreg[k + 3], e3);
            }
            float ee = (e0 + e1) + (e2 + e3);
            float xlv = bf2f(C[(size_t)s * STRIDE + t]);
            float m = xlv + xr_t + ee;
            float g = fmaxf(m, 0.2f * m);         // leaky_relu(0.2)
            float p = g * att_t;
            p += __shfl_xor(p, 1, 64);
            p += __shfl_xor(p, 2, 64);
            p += __shfl_xor(p, 4, 64);
            p += __shfl_xor(p, 8, 64);
            p += __shfl_xor(p, 16, 64);           // sum over 32-lane head group
            float pe = __expf(p);
            l_run += pe;
            acc = fmaf(pe, xlv, acc);
        }

        float o = acc / (l_run + 1e-16f) + bias_t;
        o = o > 0.f ? o : (__expf(o) - 1.f);                 // ELU
        float v = o + bf2f(resid[(size_t)i * rstride + t]);  // + residual
        float mean = block_sum128(v, red) * (1.f / 128.f);
        float d = v - mean;
        float var = block_sum128(d * d, red) * (1.f / 128.f);
        float r = d * rsqrtf(var + 1e-5f) * gamma_t + beta_t;
        outb[(size_t)i * 128 + t] = f2bf(r);
        __syncthreads();
    }
}

// ---------------- plain LN over 128 ----------------
__global__ __launch_bounds__(128) void k_ln(const float* __restrict__ in,
                                            const float* __restrict__ gamma,
                                            const float* __restrict__ beta,
                                            float* __restrict__ out) {
    __shared__ float red[2];
    int i = blockIdx.x, t = threadIdx.x;
    float v = in[(size_t)i * 128 + t];
    float mean = block_sum128(v, red) * (1.f / 128.f);
    float d = v - mean;
    float var = block_sum128(d * d, red) * (1.f / 128.f);
    out[(size_t)i * 128 + t] = d * rsqrtf(var + 1e-5f) * gamma[t] + beta[t];
}

extern "C" void kernel_launch(void* const* d_in, const int* in_sizes, int n_in,
                              void* d_out, int out_size, void* d_ws, size_t ws_size,
                              hipStream_t stream) {
    (void)in_sizes; (void)n_in; (void)out_size; (void)ws_size;
    const float* x     = (const float*)d_in[0];
    const float* ea    = (const float*)d_in[1];
    const float* Wl1   = (const float*)d_in[2];
    const float* bl1   = (const float*)d_in[3];
    const float* Wr1   = (const float*)d_in[4];
    const float* br1   = (const float*)d_in[5];
    const float* We1   = (const float*)d_in[6];
    const float* att1  = (const float*)d_in[7];
    const float* bias1 = (const float*)d_in[8];
    const float* Wl2   = (const float*)d_in[9];
    const float* bl2   = (const float*)d_in[10];
    const float* Wr2   = (const float*)d_in[11];
    const float* br2   = (const float*)d_in[12];
    const float* We2   = (const float*)d_in[13];
    const float* att2  = (const float*)d_in[14];
    const float* bias2 = (const float*)d_in[15];
    const float* Wres  = (const float*)d_in[16];
    const float* bres  = (const float*)d_in[17];
    const float* Wout  = (const float*)d_in[18];
    const float* bout  = (const float*)d_in[19];
    const float* g1    = (const float*)d_in[20];
    const float* bn1   = (const float*)d_in[21];
    const float* g2    = (const float*)d_in[22];
    const float* bn2   = (const float*)d_in[23];
    const float* go    = (const float*)d_in[24];
    const float* bo    = (const float*)d_in[25];
    const int*   ei    = (const int*)d_in[26];
    const int* srcv = ei;
    const int* dstv = ei + NE;
    float* outp = (float*)d_out;

    char* p = (char*)d_ws;
    auto carve = [&](size_t bytes) {
        char* r = p;
        p += (bytes + 255) & ~(size_t)255;
        return r;
    };
    short* xb    = (short*)carve((size_t)NN * KP1 * 2);
    short* Wt1   = (short*)carve((size_t)384 * KP1 * 2);
    short* Wt2   = (short*)carve((size_t)256 * 128 * 2);
    short* Wt3   = (short*)carve((size_t)128 * 128 * 2);
    float* bcat1 = (float*)carve(384 * 4);
    float* bcat2 = (float*)carve(256 * 4);
    short* C1    = (short*)carve((size_t)NN * 384 * 2);   // bf16 [xl|xr|res]
    short* h1b   = (short*)carve((size_t)NN * 128 * 2);
    short* h2b   = (short*)carve((size_t)NN * 128 * 2);
    float* C3    = (float*)carve((size_t)NN * 128 * 4);
    int* off     = (int*)carve((size_t)(NN + 1) * 4);
    int* cur     = (int*)carve((size_t)NN * 4);
    int* bsum    = (int*)carve(256 * 4);
    int2* csr_se = (int2*)carve((size_t)NE * 8);

    short* C2 = C1;                                  // stride 256, reuse after layer 1

    const int NB = (NN + 255) / 256;                 // 196

    // ---- CSR build ----
    hipMemsetAsync(cur, 0, (size_t)NN * 4, stream);
    k_count<<<(NE + 255) / 256, 256, 0, stream>>>(dstv, cur);
    k_scan1<<<NB, 256, 0, stream>>>(cur, off, bsum);
    k_scan2<<<1, 256, 0, stream>>>(bsum, NB);
    k_scan3c<<<(NN + 256) / 256, 256, 0, stream>>>(off, bsum, cur);
    k_scatter<<<(NE + 255) / 256, 256, 0, stream>>>(srcv, dstv, cur, csr_se);

    // ---- prep ----
    k_cvt_x<<<((size_t)NN * KP1 + 255) / 256, 256, 0, stream>>>(x, xb);
    int prep_total = 384 * KP1 + 256 * 128 + 128 * 128 + 384 + 256;
    k_prep_w<<<(prep_total + 255) / 256, 256, 0, stream>>>(Wl1, Wr1, Wres, Wl2, Wr2, Wout,
                                                           bl1, br1, bres, bl2, br2,
                                                           Wt1, Wt2, Wt3, bcat1, bcat2);

    int mb = (NN + 127) / 128;                       // 391

    // ---- layer 1 ----
    k_mfma_gemm<true><<<dim3(mb, 3), 256, 0, stream>>>(xb, Wt1, bcat1, nullptr, C1, NN, KP1, 384);
    k_fused_agg<384, 4><<<NN / 4, 128, 0, stream>>>(off, csr_se, C1, ea, We1, att1,
                                                    C1 + 256, 384, bias1, g1, bn1, h1b);
    // ---- layer 2 ----
    k_mfma_gemm<true><<<dim3(mb, 2), 256, 0, stream>>>(h1b, Wt2, bcat2, nullptr, C2, NN, 128, 256);
    k_fused_agg<256, 4><<<NN / 4, 128, 0, stream>>>(off, csr_se, C2, ea, We2, att2,
                                                    h1b, 128, bias2, g2, bn2, h2b);
    // ---- output ----
    k_mfma_gemm<false><<<dim3(mb, 1), 256, 0, stream>>>(h2b, Wt3, bout, C3, nullptr, NN, 128, 128);
    k_ln<<<NN, 128, 0, stream>>>(C3, go, bo, outp);
}

// Round 7
// 536.038 us; speedup vs baseline: 1.1842x; 1.0980x over previous
//
#include <hip/hip_runtime.h>
#include <hip/hip_bf16.h>
#include <math.h>
#include <stdint.h>

#define NN 50000
#define NE 500000
#define DIN 264
#define KP1 288      // DIN padded to multiple of 32
#define HID 128
#define EDIM 16

typedef __attribute__((ext_vector_type(8))) short short8;
typedef __attribute__((ext_vector_type(4))) float f32x4;

__device__ __forceinline__ short f2bf(float v) {
    union { float f; unsigned u; } x; x.f = v;
    unsigned r = x.u + 0x7fff + ((x.u >> 16) & 1);
    return (short)(r >> 16);
}
__device__ __forceinline__ float bf2f(short v) {
    union { float f; unsigned u; } x;
    x.u = ((unsigned)(unsigned short)v) << 16;
    return x.f;
}

__device__ __forceinline__ void gload_lds16(const void* g, void* l) {
    __builtin_amdgcn_global_load_lds(
        (const __attribute__((address_space(1))) unsigned int*)g,
        (__attribute__((address_space(3))) unsigned int*)l, 16, 0, 0);
}

// ---------------- CSR build (dst -> in-edges) ----------------
__global__ void k_count(const int* __restrict__ dst, int* __restrict__ cnt) {
    int e = blockIdx.x * blockDim.x + threadIdx.x;
    if (e < NE) atomicAdd(&cnt[dst[e]], 1);
}

__global__ __launch_bounds__(256) void k_scan1(const int* __restrict__ cnt,
                                               int* __restrict__ off, int* __restrict__ bsum) {
    __shared__ int buf[256];
    int b = blockIdx.x, t = threadIdx.x;
    int i = b * 256 + t;
    int v = (i < NN) ? cnt[i] : 0;
    buf[t] = v; __syncthreads();
    for (int s = 1; s < 256; s <<= 1) {
        int u = (t >= s) ? buf[t - s] : 0; __syncthreads();
        buf[t] += u; __syncthreads();
    }
    if (i < NN) off[i + 1] = buf[t];
    if (t == 255) bsum[b] = buf[255];
}

__global__ void k_scan2(int* __restrict__ bsum, int nb) {
    __shared__ int buf[256];
    int t = threadIdx.x;
    int o = (t < nb) ? bsum[t] : 0;
    buf[t] = o; __syncthreads();
    for (int s = 1; s < 256; s <<= 1) {
        int u = (t >= s) ? buf[t - s] : 0; __syncthreads();
        buf[t] += u; __syncthreads();
    }
    if (t < nb) bsum[t] = buf[t] - o;   // exclusive
}

// finalize offsets AND copy to cur in one pass
__global__ void k_scan3c(int* __restrict__ off, const int* __restrict__ bsum,
                         int* __restrict__ cur) {
    int j = blockIdx.x * 256 + threadIdx.x;   // 0..NN
    if (j > NN) return;
    int v = (j == 0) ? 0 : off[j] + bsum[(j - 1) >> 8];
    off[j] = v;
    if (j < NN) cur[j] = v;
}

__global__ void k_scatter(const int* __restrict__ src, const int* __restrict__ dst,
                          int* __restrict__ cur, int2* __restrict__ csr_se) {
    int e = blockIdx.x * blockDim.x + threadIdx.x;
    if (e < NE) {
        int d = dst[e];
        int p = atomicAdd(&cur[d], 1);
        csr_se[p] = make_int2(src[e], e);
    }
}

// ---------------- weight/bias/input prep ----------------
__global__ void k_cvt_x(const float* __restrict__ x, short* __restrict__ xb) {
    int idx = blockIdx.x * 256 + threadIdx.x;
    if (idx >= NN * KP1) return;
    int i = idx / KP1, k = idx - i * KP1;
    xb[idx] = (k < DIN) ? f2bf(x[(size_t)i * DIN + k]) : (short)0;
}

// all weight transposes + bias concats in ONE dispatch
__global__ void k_prep_w(const float* __restrict__ Wl1, const float* __restrict__ Wr1,
                         const float* __restrict__ Wres, const float* __restrict__ Wl2,
                         const float* __restrict__ Wr2, const float* __restrict__ Wout,
                         const float* __restrict__ bl1, const float* __restrict__ br1,
                         const float* __restrict__ bres, const float* __restrict__ bl2,
                         const float* __restrict__ br2,
                         short* __restrict__ Wt1, short* __restrict__ Wt2,
                         short* __restrict__ Wt3, float* __restrict__ bcat1,
                         float* __restrict__ bcat2) {
    int idx = blockIdx.x * 256 + threadIdx.x;
    if (idx < 384 * KP1) {
        int n = idx / KP1, k = idx - n * KP1;
        float v = 0.f;
        if (k < DIN) {
            const float* W = (n < 128) ? Wl1 : ((n < 256) ? Wr1 : Wres);
            v = W[(size_t)k * 128 + (n & 127)];
        }
        Wt1[idx] = f2bf(v);
        return;
    }
    idx -= 384 * KP1;
    if (idx < 256 * 128) {
        int n = idx >> 7, k = idx & 127;
        const float* W = (n < 128) ? Wl2 : Wr2;
        Wt2[idx] = f2bf(W[(size_t)k * 128 + (n & 127)]);
        return;
    }
    idx -= 256 * 128;
    if (idx < 128 * 128) {
        int n = idx >> 7, k = idx & 127;
        Wt3[idx] = f2bf(Wout[(size_t)k * 128 + n]);
        return;
    }
    idx -= 128 * 128;
    if (idx < 384) {
        bcat1[idx] = (idx < 128) ? bl1[idx] : ((idx < 256) ? br1[idx - 128] : bres[idx - 256]);
        return;
    }
    idx -= 384;
    if (idx < 256)
        bcat2[idx] = (idx < 128) ? bl2[idx] : br2[idx - 128];
}

// ---------------- bf16 MFMA GEMM: C[M x NS] = A[M x Kpad] @ Bt[NS x Kpad]^T + bias ----------------
template <bool BF16OUT>
__global__ __launch_bounds__(256) void k_mfma_gemm(const short* __restrict__ A,
                                                   const short* __restrict__ Bt,
                                                   const float* __restrict__ bias,
                                                   float* __restrict__ Cf,
                                                   short* __restrict__ Cb,
                                                   int M, int Kpad, int NS) {
    __shared__ short As[128 * 32];
    __shared__ short Bs[128 * 32];
    int t = threadIdx.x;
    int lane = t & 63, wid = t >> 6;
    int wm = (wid & 1) * 64, wn = (wid >> 1) * 64;
    int cl = lane & 15, quad = lane >> 4;
    int row0 = blockIdx.x * 128;
    int col0 = blockIdx.y * 128;

    f32x4 acc[4][4];
#pragma unroll
    for (int i = 0; i < 4; ++i)
#pragma unroll
        for (int j = 0; j < 4; ++j) acc[i][j] = (f32x4)0.f;

    for (int k0 = 0; k0 < Kpad; k0 += 32) {
#pragma unroll
        for (int r = 0; r < 2; ++r) {
            int c = t + r * 256;                     // chunk 0..511
            int m = c >> 2;
            int row = row0 + m; if (row >= M) row = M - 1;
            const char* ga = (const char*)A + ((size_t)row * Kpad + k0) * 2 + (c & 3) * 16;
            gload_lds16(ga, (char*)As + c * 16);
            int n = col0 + m;
            const char* gb = (const char*)Bt + ((size_t)n * Kpad + k0) * 2 + (c & 3) * 16;
            gload_lds16(gb, (char*)Bs + c * 16);
        }
        __syncthreads();

        short8 a[4], b[4];
#pragma unroll
        for (int mi = 0; mi < 4; ++mi)
            a[mi] = *(const short8*)&As[(wm + mi * 16 + cl) * 32 + quad * 8];
#pragma unroll
        for (int ni = 0; ni < 4; ++ni)
            b[ni] = *(const short8*)&Bs[(wn + ni * 16 + cl) * 32 + quad * 8];
#pragma unroll
        for (int mi = 0; mi < 4; ++mi)
#pragma unroll
            for (int ni = 0; ni < 4; ++ni)
                acc[mi][ni] = __builtin_amdgcn_mfma_f32_16x16x32_bf16(a[mi], b[ni], acc[mi][ni], 0, 0, 0);
        __syncthreads();
    }

#pragma unroll
    for (int mi = 0; mi < 4; ++mi)
#pragma unroll
        for (int ni = 0; ni < 4; ++ni) {
            int col = col0 + wn + ni * 16 + cl;
            float bv = bias[col];
#pragma unroll
            for (int r = 0; r < 4; ++r) {
                int row = row0 + wm + mi * 16 + quad * 4 + r;
                if (row < M) {
                    float v = acc[mi][ni][r] + bv;
                    if (BF16OUT) Cb[(size_t)row * NS + col] = f2bf(v);
                    else         Cf[(size_t)row * NS + col] = v;
                }
            }
        }
}

// ---------------- block helpers ----------------
__device__ __forceinline__ float block_sum128(float v, volatile float* red) {
#pragma unroll
    for (int o = 32; o > 0; o >>= 1) v += __shfl_down(v, o, 64);
    int w = threadIdx.x >> 6;
    __syncthreads();
    if ((threadIdx.x & 63) == 0) red[w] = v;
    __syncthreads();
    return red[0] + red[1];
}

// ---------------- fused edge-score + softmax aggregate + epilogue ----------------
// One block (128 thr) per NPB consecutive dst nodes; thread t owns feature t.
// Plain-sum softmax (scores O(1)); all per-edge loads are VECTOR loads
// (csr_se/ea broadcast, xl gather) so the compiler pipelines via vmcnt;
// manual 2-edge unroll issues both edges' loads before either compute.
template <int STRIDE, int NPB>
__global__ __launch_bounds__(128) void k_fused_agg(const int* __restrict__ off,
                                                   const int2* __restrict__ csr_se,
                                                   const short* __restrict__ C,
                                                   const float* __restrict__ ea,
                                                   const float* __restrict__ We,
                                                   const float* __restrict__ att,
                                                   const short* __restrict__ resid, int rstride,
                                                   const float* __restrict__ bias,
                                                   const float* __restrict__ gamma,
                                                   const float* __restrict__ beta,
                                                   short* __restrict__ outb) {
    __shared__ float red[2];
    int t = threadIdx.x;

    float wreg[EDIM];
#pragma unroll
    for (int k = 0; k < EDIM; ++k) wreg[k] = We[k * 128 + t];
    float att_t = att[t], bias_t = bias[t], gamma_t = gamma[t], beta_t = beta[t];

    for (int n = 0; n < NPB; ++n) {
        int i = blockIdx.x * NPB + n;
        int b0 = off[i], b1 = off[i + 1];
        float xr_t = bf2f(C[(size_t)i * STRIDE + 128 + t]);

        float l_run = 0.f, acc = 0.f;
        int pos = b0;
        for (; pos + 2 <= b1; pos += 2) {
            // issue ALL loads for both edges first
            int2 seA = csr_se[pos];
            int2 seB = csr_se[pos + 1];
            const float4* eaA = (const float4*)(ea + (size_t)seA.y * EDIM);
            const float4* eaB = (const float4*)(ea + (size_t)seB.y * EDIM);
            float4 A0 = eaA[0], A1 = eaA[1], A2 = eaA[2], A3 = eaA[3];
            float4 B0 = eaB[0], B1 = eaB[1], B2 = eaB[2], B3 = eaB[3];
            float xlA = bf2f(C[(size_t)seA.x * STRIDE + t]);
            float xlB = bf2f(C[(size_t)seB.x * STRIDE + t]);
            // edge A
            float eA = A0.x * wreg[0];
            eA = fmaf(A0.y, wreg[1], eA);  eA = fmaf(A0.z, wreg[2], eA);
            eA = fmaf(A0.w, wreg[3], eA);  eA = fmaf(A1.x, wreg[4], eA);
            eA = fmaf(A1.y, wreg[5], eA);  eA = fmaf(A1.z, wreg[6], eA);
            eA = fmaf(A1.w, wreg[7], eA);  eA = fmaf(A2.x, wreg[8], eA);
            eA = fmaf(A2.y, wreg[9], eA);  eA = fmaf(A2.z, wreg[10], eA);
            eA = fmaf(A2.w, wreg[11], eA); eA = fmaf(A3.x, wreg[12], eA);
            eA = fmaf(A3.y, wreg[13], eA); eA = fmaf(A3.z, wreg[14], eA);
            eA = fmaf(A3.w, wreg[15], eA);
            float mA = xlA + xr_t + eA;
            float pA = fmaxf(mA, 0.2f * mA) * att_t;
            // edge B
            float eB = B0.x * wreg[0];
            eB = fmaf(B0.y, wreg[1], eB);  eB = fmaf(B0.z, wreg[2], eB);
            eB = fmaf(B0.w, wreg[3], eB);  eB = fmaf(B1.x, wreg[4], eB);
            eB = fmaf(B1.y, wreg[5], eB);  eB = fmaf(B1.z, wreg[6], eB);
            eB = fmaf(B1.w, wreg[7], eB);  eB = fmaf(B2.x, wreg[8], eB);
            eB = fmaf(B2.y, wreg[9], eB);  eB = fmaf(B2.z, wreg[10], eB);
            eB = fmaf(B2.w, wreg[11], eB); eB = fmaf(B3.x, wreg[12], eB);
            eB = fmaf(B3.y, wreg[13], eB); eB = fmaf(B3.z, wreg[14], eB);
            eB = fmaf(B3.w, wreg[15], eB);
            float mB = xlB + xr_t + eB;
            float pB = fmaxf(mB, 0.2f * mB) * att_t;
            // interleaved head reductions (independent shfl chains)
            pA += __shfl_xor(pA, 1, 64);  pB += __shfl_xor(pB, 1, 64);
            pA += __shfl_xor(pA, 2, 64);  pB += __shfl_xor(pB, 2, 64);
            pA += __shfl_xor(pA, 4, 64);  pB += __shfl_xor(pB, 4, 64);
            pA += __shfl_xor(pA, 8, 64);  pB += __shfl_xor(pB, 8, 64);
            pA += __shfl_xor(pA, 16, 64); pB += __shfl_xor(pB, 16, 64);
            float peA = __expf(pA), peB = __expf(pB);
            l_run += peA + peB;
            acc = fmaf(peA, xlA, acc);
            acc = fmaf(peB, xlB, acc);
        }
        if (pos < b1) {
            int2 se = csr_se[pos];
            const float4* ea4 = (const float4*)(ea + (size_t)se.y * EDIM);
            float4 A0 = ea4[0], A1 = ea4[1], A2 = ea4[2], A3 = ea4[3];
            float xlv = bf2f(C[(size_t)se.x * STRIDE + t]);
            float ee = A0.x * wreg[0];
            ee = fmaf(A0.y, wreg[1], ee);  ee = fmaf(A0.z, wreg[2], ee);
            ee = fmaf(A0.w, wreg[3], ee);  ee = fmaf(A1.x, wreg[4], ee);
            ee = fmaf(A1.y, wreg[5], ee);  ee = fmaf(A1.z, wreg[6], ee);
            ee = fmaf(A1.w, wreg[7], ee);  ee = fmaf(A2.x, wreg[8], ee);
            ee = fmaf(A2.y, wreg[9], ee);  ee = fmaf(A2.z, wreg[10], ee);
            ee = fmaf(A2.w, wreg[11], ee); ee = fmaf(A3.x, wreg[12], ee);
            ee = fmaf(A3.y, wreg[13], ee); ee = fmaf(A3.z, wreg[14], ee);
            ee = fmaf(A3.w, wreg[15], ee);
            float m = xlv + xr_t + ee;
            float p = fmaxf(m, 0.2f * m) * att_t;
            p += __shfl_xor(p, 1, 64);
            p += __shfl_xor(p, 2, 64);
            p += __shfl_xor(p, 4, 64);
            p += __shfl_xor(p, 8, 64);
            p += __shfl_xor(p, 16, 64);
            float pe = __expf(p);
            l_run += pe;
            acc = fmaf(pe, xlv, acc);
        }

        float o = acc / (l_run + 1e-16f) + bias_t;
        o = o > 0.f ? o : (__expf(o) - 1.f);                 // ELU
        float v = o + bf2f(resid[(size_t)i * rstride + t]);  // + residual
        float mean = block_sum128(v, red) * (1.f / 128.f);
        float d = v - mean;
        float var = block_sum128(d * d, red) * (1.f / 128.f);
        float r = d * rsqrtf(var + 1e-5f) * gamma_t + beta_t;
        outb[(size_t)i * 128 + t] = f2bf(r);
    }
}

// ---------------- plain LN over 128 ----------------
__global__ __launch_bounds__(128) void k_ln(const float* __restrict__ in,
                                            const float* __restrict__ gamma,
                                            const float* __restrict__ beta,
                                            float* __restrict__ out) {
    __shared__ float red[2];
    int i = blockIdx.x, t = threadIdx.x;
    float v = in[(size_t)i * 128 + t];
    float mean = block_sum128(v, red) * (1.f / 128.f);
    float d = v - mean;
    float var = block_sum128(d * d, red) * (1.f / 128.f);
    out[(size_t)i * 128 + t] = d * rsqrtf(var + 1e-5f) * gamma[t] + beta[t];
}

extern "C" void kernel_launch(void* const* d_in, const int* in_sizes, int n_in,
                              void* d_out, int out_size, void* d_ws, size_t ws_size,
                              hipStream_t stream) {
    (void)in_sizes; (void)n_in; (void)out_size; (void)ws_size;
    const float* x     = (const float*)d_in[0];
    const float* ea    = (const float*)d_in[1];
    const float* Wl1   = (const float*)d_in[2];
    const float* bl1   = (const float*)d_in[3];
    const float* Wr1   = (const float*)d_in[4];
    const float* br1   = (const float*)d_in[5];
    const float* We1   = (const float*)d_in[6];
    const float* att1  = (const float*)d_in[7];
    const float* bias1 = (const float*)d_in[8];
    const float* Wl2   = (const float*)d_in[9];
    const float* bl2   = (const float*)d_in[10];
    const float* Wr2   = (const float*)d_in[11];
    const float* br2   = (const float*)d_in[12];
    const float* We2   = (const float*)d_in[13];
    const float* att2  = (const float*)d_in[14];
    const float* bias2 = (const float*)d_in[15];
    const float* Wres  = (const float*)d_in[16];
    const float* bres  = (const float*)d_in[17];
    const float* Wout  = (const float*)d_in[18];
    const float* bout  = (const float*)d_in[19];
    const float* g1    = (const float*)d_in[20];
    const float* bn1   = (const float*)d_in[21];
    const float* g2    = (const float*)d_in[22];
    const float* bn2   = (const float*)d_in[23];
    const float* go    = (const float*)d_in[24];
    const float* bo    = (const float*)d_in[25];
    const int*   ei    = (const int*)d_in[26];
    const int* srcv = ei;
    const int* dstv = ei + NE;
    float* outp = (float*)d_out;

    char* p = (char*)d_ws;
    auto carve = [&](size_t bytes) {
        char* r = p;
        p += (bytes + 255) & ~(size_t)255;
        return r;
    };
    short* xb    = (short*)carve((size_t)NN * KP1 * 2);
    short* Wt1   = (short*)carve((size_t)384 * KP1 * 2);
    short* Wt2   = (short*)carve((size_t)256 * 128 * 2);
    short* Wt3   = (short*)carve((size_t)128 * 128 * 2);
    float* bcat1 = (float*)carve(384 * 4);
    float* bcat2 = (float*)carve(256 * 4);
    short* C1    = (short*)carve((size_t)NN * 384 * 2);   // bf16 [xl|xr|res]
    short* h1b   = (short*)carve((size_t)NN * 128 * 2);
    short* h2b   = (short*)carve((size_t)NN * 128 * 2);
    float* C3    = (float*)carve((size_t)NN * 128 * 4);
    int* off     = (int*)carve((size_t)(NN + 1) * 4);
    int* cur     = (int*)carve((size_t)NN * 4);
    int* bsum    = (int*)carve(256 * 4);
    int2* csr_se = (int2*)carve((size_t)NE * 8);

    short* C2 = C1;                                  // stride 256, reuse after layer 1

    const int NB = (NN + 255) / 256;                 // 196

    // ---- CSR build ----
    hipMemsetAsync(cur, 0, (size_t)NN * 4, stream);
    k_count<<<(NE + 255) / 256, 256, 0, stream>>>(dstv, cur);
    k_scan1<<<NB, 256, 0, stream>>>(cur, off, bsum);
    k_scan2<<<1, 256, 0, stream>>>(bsum, NB);
    k_scan3c<<<(NN + 256) / 256, 256, 0, stream>>>(off, bsum, cur);
    k_scatter<<<(NE + 255) / 256, 256, 0, stream>>>(srcv, dstv, cur, csr_se);

    // ---- prep ----
    k_cvt_x<<<((size_t)NN * KP1 + 255) / 256, 256, 0, stream>>>(x, xb);
    int prep_total = 384 * KP1 + 256 * 128 + 128 * 128 + 384 + 256;
    k_prep_w<<<(prep_total + 255) / 256, 256, 0, stream>>>(Wl1, Wr1, Wres, Wl2, Wr2, Wout,
                                                           bl1, br1, bres, bl2, br2,
                                                           Wt1, Wt2, Wt3, bcat1, bcat2);

    int mb = (NN + 127) / 128;                       // 391

    // ---- layer 1 ----
    k_mfma_gemm<true><<<dim3(mb, 3), 256, 0, stream>>>(xb, Wt1, bcat1, nullptr, C1, NN, KP1, 384);
    k_fused_agg<384, 4><<<NN / 4, 128, 0, stream>>>(off, csr_se, C1, ea, We1, att1,
                                                    C1 + 256, 384, bias1, g1, bn1, h1b);
    // ---- layer 2 ----
    k_mfma_gemm<true><<<dim3(mb, 2), 256, 0, stream>>>(h1b, Wt2, bcat2, nullptr, C2, NN, 128, 256);
    k_fused_agg<256, 4><<<NN / 4, 128, 0, stream>>>(off, csr_se, C2, ea, We2, att2,
                                                    h1b, 128, bias2, g2, bn2, h2b);
    // ---- output ----
    k_mfma_gemm<false><<<dim3(mb, 1), 256, 0, stream>>>(h2b, Wt3, bout, C3, nullptr, NN, 128, 128);
    k_ln<<<NN, 128, 0, stream>>>(C3, go, bo, outp);
}